// Round 3
// baseline (666.997 us; speedup 1.0000x reference)
//
#include <hip/hip_runtime.h>
#include <hip/hip_bf16.h>
#include <math.h>

#define N_NODES 50000
#define N_EDGES 800000
#define DIM 256
#define MPAD 50048   /* 782*64 */
#define LN_EPS 1e-5f

typedef short bf16x8 __attribute__((ext_vector_type(8)));
typedef float f32x4 __attribute__((ext_vector_type(4)));
typedef unsigned short u16;
typedef u16 u16x8 __attribute__((ext_vector_type(8)));

__device__ __forceinline__ u16 f2bf(float f) {
    union { float f; unsigned u; } v; v.f = f;
    unsigned r = (v.u + 0x7FFFu + ((v.u >> 16) & 1u)) >> 16;
    return (u16)r;
}
__device__ __forceinline__ float bf2f(u16 h) {
    union { unsigned u; float f; } v; v.u = ((unsigned)h) << 16;
    return v.f;
}

// ---------------- CSR build ----------------
__global__ void count_kernel(const int* __restrict__ dst, int* __restrict__ counts) {
    int e = blockIdx.x * 256 + threadIdx.x;
    if (e < N_EDGES) atomicAdd(&counts[dst[e]], 1);
}

__global__ void scan_kernel(const int* __restrict__ counts, int* __restrict__ offsets,
                            int* __restrict__ cursor) {
    __shared__ int lsum[1024];
    int tid = threadIdx.x;
    const int PER = (N_NODES + 1023) / 1024;  // 49
    int start = tid * PER;
    int end = min(start + PER, N_NODES);
    int s = 0;
    for (int i = start; i < end; ++i) s += counts[i];
    lsum[tid] = s;
    __syncthreads();
    for (int off = 1; off < 1024; off <<= 1) {
        int v = (tid >= off) ? lsum[tid - off] : 0;
        __syncthreads();
        lsum[tid] += v;
        __syncthreads();
    }
    int run = lsum[tid] - s;  // exclusive prefix
    for (int i = start; i < end; ++i) {
        offsets[i] = run; cursor[i] = run;
        run += counts[i];
    }
    if (tid == 1023) offsets[N_NODES] = lsum[1023];
}

__global__ void scatter_kernel(const int* __restrict__ src, const int* __restrict__ dst,
                               const float* __restrict__ w, int* __restrict__ cursor,
                               int* __restrict__ sperm, float* __restrict__ wperm) {
    int e = blockIdx.x * 256 + threadIdx.x;
    if (e < N_EDGES) {
        int d = dst[e];
        int p = atomicAdd(&cursor[d], 1);
        sperm[p] = src[e];
        wperm[p] = w[e];
    }
}

// ---------------- f32 -> bf16 row conversion ----------------
__global__ void conv_kernel(const float* __restrict__ in, u16* __restrict__ out) {
    int i = blockIdx.x * 256 + threadIdx.x;  // covers N_NODES*256/4 elements
    float4 v = ((const float4*)in)[i];
    ushort4 o;
    o.x = f2bf(v.x); o.y = f2bf(v.y); o.z = f2bf(v.z); o.w = f2bf(v.w);
    ((ushort4*)out)[i] = o;
}

// ---------------- weight transpose + bf16 convert ----------------
// WT[m][n][k] = bf16(W_m[k][n]);  m in {0:W1, 1:W2, 2:Wp}
__global__ void convw_kernel(const float* __restrict__ W1, const float* __restrict__ W2,
                             const float* __restrict__ Wp, u16* __restrict__ WT) {
    int idx = blockIdx.x * 256 + threadIdx.x;  // 0..196607
    int m = idx >> 16;
    int r = idx & 65535;
    int n = r >> 8, k = r & 255;
    const float* W = (m == 0) ? W1 : (m == 1) ? W2 : Wp;
    WT[idx] = f2bf(W[k * 256 + n]);
}

// ---------------- SPMM: y[i] = x[i] + sum_{e: dst=i} w_e * x[src_e]  ----
// bf16 in, bf16 out. One wave per node, 4-way unrolled edge loop for MLP.
__global__ __launch_bounds__(256) void spmm_kernel(
        const u16* __restrict__ x, const int* __restrict__ offs,
        const int* __restrict__ sperm, const float* __restrict__ wperm,
        u16* __restrict__ y) {
    int wave = threadIdx.x >> 6;
    int lane = threadIdx.x & 63;
    int node = blockIdx.x * 4 + wave;
    if (node >= N_NODES) return;

    const ushort4* xv = (const ushort4*)x;
    ushort4 v = xv[(size_t)node * 64 + lane];
    float a0 = bf2f(v.x), a1 = bf2f(v.y), a2 = bf2f(v.z), a3 = bf2f(v.w);
    float b0 = 0, b1 = 0, b2 = 0, b3 = 0;
    float c0 = 0, c1 = 0, c2 = 0, c3 = 0;
    float d0 = 0, d1 = 0, d2 = 0, d3 = 0;

    int p = offs[node];
    int p1 = offs[node + 1];
    for (; p + 4 <= p1; p += 4) {
        int s0 = sperm[p], s1 = sperm[p + 1], s2 = sperm[p + 2], s3 = sperm[p + 3];
        float w0 = wperm[p], w1 = wperm[p + 1], w2 = wperm[p + 2], w3 = wperm[p + 3];
        ushort4 v0 = xv[(size_t)s0 * 64 + lane];
        ushort4 v1 = xv[(size_t)s1 * 64 + lane];
        ushort4 v2 = xv[(size_t)s2 * 64 + lane];
        ushort4 v3 = xv[(size_t)s3 * 64 + lane];
        a0 += w0 * bf2f(v0.x); a1 += w0 * bf2f(v0.y); a2 += w0 * bf2f(v0.z); a3 += w0 * bf2f(v0.w);
        b0 += w1 * bf2f(v1.x); b1 += w1 * bf2f(v1.y); b2 += w1 * bf2f(v1.z); b3 += w1 * bf2f(v1.w);
        c0 += w2 * bf2f(v2.x); c1 += w2 * bf2f(v2.y); c2 += w2 * bf2f(v2.z); c3 += w2 * bf2f(v2.w);
        d0 += w3 * bf2f(v3.x); d1 += w3 * bf2f(v3.y); d2 += w3 * bf2f(v3.z); d3 += w3 * bf2f(v3.w);
    }
    for (; p < p1; ++p) {
        int s = sperm[p];
        float w = wperm[p];
        ushort4 vv = xv[(size_t)s * 64 + lane];
        a0 += w * bf2f(vv.x); a1 += w * bf2f(vv.y); a2 += w * bf2f(vv.z); a3 += w * bf2f(vv.w);
    }
    a0 += b0 + c0 + d0; a1 += b1 + c1 + d1;
    a2 += b2 + c2 + d2; a3 += b3 + c3 + d3;
    ushort4 o;
    o.x = f2bf(a0); o.y = f2bf(a1); o.z = f2bf(a2); o.w = f2bf(a3);
    ((ushort4*)(y + (size_t)node * 256))[lane] = o;
}

// ---------------- GEMM: LDS-free, direct MFMA-fragment loads ----------------
// 64 rows/block, 1 wave = 16 rows x 256 cols. A and BT are both row-major with
// 256-elem rows, so each lane's MFMA fragment is ONE contiguous 16B global load:
//   A-frag:  A [(row0+l15)*256 + kb*32 + quad*8]
//   B-frag:  BT[(t*16+l15)*256 + kb*32 + quad*8]
// No LDS, no barriers -> compiler pipelines loads across K; latency hidden by
// ~12 waves/CU each with dozens of loads in flight (vs 96B/wave in the old
// 2-barrier structure that measured 303 GB/s).
// MODE 0: xb_out = bf16(gelu(LN(A@B + bias)))   (rows to MPAD, no guard)
// MODE 1: f_out  = A@B + bias                   (guard row < N_NODES)
template <int MODE>
__global__ __launch_bounds__(256, 2) void gemm_kernel(
        const u16* __restrict__ A, const u16* __restrict__ BT,
        const float* __restrict__ bias, const float* __restrict__ g,
        const float* __restrict__ be, u16* __restrict__ xb_out,
        float* __restrict__ f_out) {
    int tid = threadIdx.x;
    int wave = tid >> 6, lane = tid & 63;
    int quad = lane >> 4, l15 = lane & 15;
    int row0 = blockIdx.x * 64 + wave * 16;

    const u16* ga = A + (size_t)(row0 + l15) * 256 + quad * 8;
    const u16* gb = BT + (size_t)l15 * 256 + quad * 8;

    f32x4 acc[16];
#pragma unroll
    for (int t = 0; t < 16; ++t) acc[t] = {0.f, 0.f, 0.f, 0.f};

#pragma unroll 2
    for (int kb = 0; kb < 8; ++kb) {
        bf16x8 af = *(const bf16x8*)(ga + kb * 32);
#pragma unroll
        for (int t = 0; t < 16; ++t) {
            bf16x8 bf = *(const bf16x8*)(gb + (size_t)t * 4096 + kb * 32);
            acc[t] = __builtin_amdgcn_mfma_f32_16x16x32_bf16(af, bf, acc[t], 0, 0, 0);
        }
    }

    int rbase = row0 + quad * 4;
    if (MODE == 0) {
#pragma unroll
        for (int t = 0; t < 16; ++t) {
            float bv = bias[t * 16 + l15];
#pragma unroll
            for (int i = 0; i < 4; ++i) acc[t][i] += bv;
        }
#pragma unroll
        for (int i = 0; i < 4; ++i) {
            float s = 0.f, q = 0.f;
#pragma unroll
            for (int t = 0; t < 16; ++t) { float v = acc[t][i]; s += v; q += v * v; }
            for (int off = 1; off < 16; off <<= 1) {
                s += __shfl_xor(s, off);
                q += __shfl_xor(q, off);
            }
            float mu = s * (1.0f / 256.0f);
            float var = q * (1.0f / 256.0f) - mu * mu;
            float rs = rsqrtf(var + LN_EPS);
            int row = rbase + i;
#pragma unroll
            for (int t = 0; t < 16; ++t) {
                int c = t * 16 + l15;
                float v = (acc[t][i] - mu) * rs * g[c] + be[c];
                float ge = 0.5f * v * (1.0f + erff(v * 0.70710678118f));
                xb_out[(size_t)row * 256 + c] = f2bf(ge);
            }
        }
    } else {
#pragma unroll
        for (int i = 0; i < 4; ++i) {
            int row = rbase + i;
            if (row < N_NODES) {
#pragma unroll
                for (int t = 0; t < 16; ++t) {
                    int c = t * 16 + l15;
                    f_out[(size_t)row * 256 + c] = acc[t][i] + bias[c];
                }
            }
        }
    }
}

extern "C" void kernel_launch(void* const* d_in, const int* in_sizes, int n_in,
                              void* d_out, int out_size, void* d_ws, size_t ws_size,
                              hipStream_t stream) {
    const float* nodef = (const float*)d_in[0];
    const int*   src   = (const int*)d_in[1];
    const int*   dst   = (const int*)d_in[2];
    const float* ew    = (const float*)d_in[3];
    const float* W1 = (const float*)d_in[4];
    const float* b1 = (const float*)d_in[5];
    const float* g1 = (const float*)d_in[6];
    const float* be1 = (const float*)d_in[7];
    const float* W2 = (const float*)d_in[8];
    const float* b2 = (const float*)d_in[9];
    const float* g2 = (const float*)d_in[10];
    const float* be2 = (const float*)d_in[11];
    const float* Wp = (const float*)d_in[12];
    const float* bp = (const float*)d_in[13];
    float* out = (float*)d_out;

    char* ws = (char*)d_ws;
    size_t off = 0;
    auto alloc = [&](size_t bytes) -> void* {
        void* p = ws + off;
        off += (bytes + 255) & ~(size_t)255;
        return p;
    };
    u16*   ybuf    = (u16*)alloc((size_t)MPAD * 256 * 2);
    u16*   xbuf    = (u16*)alloc((size_t)MPAD * 256 * 2);
    u16*   WT      = (u16*)alloc((size_t)3 * 65536 * 2);
    int*   counts  = (int*)alloc((size_t)N_NODES * 4);
    int*   offsets = (int*)alloc((size_t)(N_NODES + 1) * 4);
    int*   cursor  = (int*)alloc((size_t)N_NODES * 4);
    int*   sperm   = (int*)alloc((size_t)N_EDGES * 4);
    float* wperm   = (float*)alloc((size_t)N_EDGES * 4);

    hipMemsetAsync(counts, 0, (size_t)N_NODES * 4, stream);
    count_kernel<<<(N_EDGES + 255) / 256, 256, 0, stream>>>(dst, counts);
    scan_kernel<<<1, 1024, 0, stream>>>(counts, offsets, cursor);
    scatter_kernel<<<(N_EDGES + 255) / 256, 256, 0, stream>>>(src, dst, ew, cursor, sperm, wperm);
    conv_kernel<<<(N_NODES * 256 / 4) / 256, 256, 0, stream>>>(nodef, xbuf);
    convw_kernel<<<768, 256, 0, stream>>>(W1, W2, Wp, WT);

    const int GB = MPAD / 64;  // 782 gemm blocks, ~3/CU
    // layer 1  (xbuf holds bf16 node features; gemm1 overwrites it after spmm consumed it)
    spmm_kernel<<<(N_NODES + 3) / 4, 256, 0, stream>>>(xbuf, offsets, sperm, wperm, ybuf);
    gemm_kernel<0><<<GB, 256, 0, stream>>>(ybuf, WT, b1, g1, be1, xbuf, nullptr);
    // layer 2
    spmm_kernel<<<(N_NODES + 3) / 4, 256, 0, stream>>>(xbuf, offsets, sperm, wperm, ybuf);
    gemm_kernel<0><<<GB, 256, 0, stream>>>(ybuf, WT + 65536, b2, g2, be2, xbuf, nullptr);
    // projection
    gemm_kernel<1><<<GB, 256, 0, stream>>>(xbuf, WT + 2 * 65536, bp, nullptr, nullptr, nullptr, out);
}

// Round 4
// 509.834 us; speedup vs baseline: 1.3083x; 1.3083x over previous
//
#include <hip/hip_runtime.h>
#include <hip/hip_bf16.h>
#include <math.h>

#define N_NODES 50000
#define N_EDGES 800000
#define DIM 256
#define MPAD 50048   /* 391*128 */
#define LN_EPS 1e-5f
#define SCAN_BLOCKS 196  /* 196*256 = 50176 >= N_NODES */

typedef short bf16x8 __attribute__((ext_vector_type(8)));
typedef float f32x4 __attribute__((ext_vector_type(4)));
typedef unsigned short u16;
typedef u16 u16x8 __attribute__((ext_vector_type(8)));

__device__ __forceinline__ u16 f2bf(float f) {
    union { float f; unsigned u; } v; v.f = f;
    unsigned r = (v.u + 0x7FFFu + ((v.u >> 16) & 1u)) >> 16;
    return (u16)r;
}
__device__ __forceinline__ float bf2f(u16 h) {
    union { unsigned u; float f; } v; v.u = ((unsigned)h) << 16;
    return v.f;
}

// ---------------- CSR build ----------------
__global__ void count_kernel(const int* __restrict__ dst, int* __restrict__ counts) {
    int e = blockIdx.x * 256 + threadIdx.x;
    if (e < N_EDGES) atomicAdd(&counts[dst[e]], 1);
}

// stage 1: per-256-chunk exclusive scan; offsets[idx] = local exclusive, bsum[b] = chunk total
__global__ void scan1_kernel(const int* __restrict__ counts, int* __restrict__ offsets,
                             int* __restrict__ bsum) {
    __shared__ int sh[256];
    int t = threadIdx.x;
    int idx = blockIdx.x * 256 + t;
    int v = (idx < N_NODES) ? counts[idx] : 0;
    sh[t] = v;
    __syncthreads();
#pragma unroll
    for (int off = 1; off < 256; off <<= 1) {
        int u = (t >= off) ? sh[t - off] : 0;
        __syncthreads();
        sh[t] += u;
        __syncthreads();
    }
    if (idx < N_NODES) offsets[idx] = sh[t] - v;  // exclusive within chunk
    if (t == 255) bsum[blockIdx.x] = sh[255];
}

// stage 2: exclusive scan of the 196 chunk totals
__global__ void scan2_kernel(const int* __restrict__ bsum, int* __restrict__ bbase) {
    __shared__ int sh[256];
    int t = threadIdx.x;
    int v = (t < SCAN_BLOCKS) ? bsum[t] : 0;
    sh[t] = v;
    __syncthreads();
#pragma unroll
    for (int off = 1; off < 256; off <<= 1) {
        int u = (t >= off) ? sh[t - off] : 0;
        __syncthreads();
        sh[t] += u;
        __syncthreads();
    }
    if (t < SCAN_BLOCKS) bbase[t] = sh[t] - v;
}

// stage 3: add chunk base; init cursor; offsets[N_NODES] = N_EDGES (every edge has a dst)
__global__ void scan3_kernel(int* __restrict__ offsets, const int* __restrict__ bbase,
                             int* __restrict__ cursor) {
    int idx = blockIdx.x * 256 + threadIdx.x;
    if (idx < N_NODES) {
        int o = offsets[idx] + bbase[blockIdx.x];
        offsets[idx] = o;
        cursor[idx] = o;
    }
    if (idx == 0) offsets[N_NODES] = N_EDGES;
}

__global__ void scatter_kernel(const int* __restrict__ src, const int* __restrict__ dst,
                               const float* __restrict__ w, int* __restrict__ cursor,
                               int* __restrict__ sperm, float* __restrict__ wperm) {
    int e = blockIdx.x * 256 + threadIdx.x;
    if (e < N_EDGES) {
        int d = dst[e];
        int p = atomicAdd(&cursor[d], 1);
        sperm[p] = src[e];
        wperm[p] = w[e];
    }
}

// ---------------- f32 -> bf16 row conversion ----------------
__global__ void conv_kernel(const float* __restrict__ in, u16* __restrict__ out) {
    int i = blockIdx.x * 256 + threadIdx.x;  // covers N_NODES*256/4 elements
    float4 v = ((const float4*)in)[i];
    ushort4 o;
    o.x = f2bf(v.x); o.y = f2bf(v.y); o.z = f2bf(v.z); o.w = f2bf(v.w);
    ((ushort4*)out)[i] = o;
}

// ---------------- weight transpose + bf16 convert ----------------
// WT[m][n][k] = bf16(W_m[k][n]);  m in {0:W1, 1:W2, 2:Wp}
__global__ void convw_kernel(const float* __restrict__ W1, const float* __restrict__ W2,
                             const float* __restrict__ Wp, u16* __restrict__ WT) {
    int idx = blockIdx.x * 256 + threadIdx.x;  // 0..196607
    int m = idx >> 16;
    int r = idx & 65535;
    int n = r >> 8, k = r & 255;
    const float* W = (m == 0) ? W1 : (m == 1) ? W2 : Wp;
    WT[idx] = f2bf(W[k * 256 + n]);
}

// ---------------- SPMM: y[i] = x[i] + sum_{e: dst=i} w_e * x[src_e]  ----
// bf16 in, bf16 out. One wave per node, 4-way unrolled edge loop for MLP.
__global__ __launch_bounds__(256) void spmm_kernel(
        const u16* __restrict__ x, const int* __restrict__ offs,
        const int* __restrict__ sperm, const float* __restrict__ wperm,
        u16* __restrict__ y) {
    int wave = threadIdx.x >> 6;
    int lane = threadIdx.x & 63;
    int node = blockIdx.x * 4 + wave;
    if (node >= N_NODES) return;

    const ushort4* xv = (const ushort4*)x;
    ushort4 v = xv[(size_t)node * 64 + lane];
    float a0 = bf2f(v.x), a1 = bf2f(v.y), a2 = bf2f(v.z), a3 = bf2f(v.w);
    float b0 = 0, b1 = 0, b2 = 0, b3 = 0;
    float c0 = 0, c1 = 0, c2 = 0, c3 = 0;
    float d0 = 0, d1 = 0, d2 = 0, d3 = 0;

    int p = offs[node];
    int p1 = offs[node + 1];
    for (; p + 4 <= p1; p += 4) {
        int s0 = sperm[p], s1 = sperm[p + 1], s2 = sperm[p + 2], s3 = sperm[p + 3];
        float w0 = wperm[p], w1 = wperm[p + 1], w2 = wperm[p + 2], w3 = wperm[p + 3];
        ushort4 v0 = xv[(size_t)s0 * 64 + lane];
        ushort4 v1 = xv[(size_t)s1 * 64 + lane];
        ushort4 v2 = xv[(size_t)s2 * 64 + lane];
        ushort4 v3 = xv[(size_t)s3 * 64 + lane];
        a0 += w0 * bf2f(v0.x); a1 += w0 * bf2f(v0.y); a2 += w0 * bf2f(v0.z); a3 += w0 * bf2f(v0.w);
        b0 += w1 * bf2f(v1.x); b1 += w1 * bf2f(v1.y); b2 += w1 * bf2f(v1.z); b3 += w1 * bf2f(v1.w);
        c0 += w2 * bf2f(v2.x); c1 += w2 * bf2f(v2.y); c2 += w2 * bf2f(v2.z); c3 += w2 * bf2f(v2.w);
        d0 += w3 * bf2f(v3.x); d1 += w3 * bf2f(v3.y); d2 += w3 * bf2f(v3.z); d3 += w3 * bf2f(v3.w);
    }
    for (; p < p1; ++p) {
        int s = sperm[p];
        float w = wperm[p];
        ushort4 vv = xv[(size_t)s * 64 + lane];
        a0 += w * bf2f(vv.x); a1 += w * bf2f(vv.y); a2 += w * bf2f(vv.z); a3 += w * bf2f(vv.w);
    }
    a0 += b0 + c0 + d0; a1 += b1 + c1 + d1;
    a2 += b2 + c2 + d2; a3 += b3 + c3 + d3;
    ushort4 o;
    o.x = f2bf(a0); o.y = f2bf(a1); o.z = f2bf(a2); o.w = f2bf(a3);
    ((ushort4*)(y + (size_t)node * 256))[lane] = o;
}

// ---------------- GEMM: LDS-free, 32 rows/wave, direct MFMA-fragment loads ----
// 128 rows/block (4 waves x 32 rows), grid 391. Each lane's fragment is one
// contiguous 16B global load; each B-fragment feeds TWO MFMAs (row-frags 0/1),
// so per kb-step: 18 loads -> 32 MFMAs (2x the density of the 16-row version).
// No LDS, no barriers -> loads pipeline freely across the unrolled K loop.
// MODE 0: xb_out = bf16(gelu(LN(A@B + bias)))   (rows to MPAD, no guard)
// MODE 1: f_out  = A@B + bias                   (guard row < N_NODES)
template <int MODE>
__global__ __launch_bounds__(256, 2) void gemm_kernel(
        const u16* __restrict__ A, const u16* __restrict__ BT,
        const float* __restrict__ bias, const float* __restrict__ g,
        const float* __restrict__ be, u16* __restrict__ xb_out,
        float* __restrict__ f_out) {
    int tid = threadIdx.x;
    int wave = tid >> 6, lane = tid & 63;
    int quad = lane >> 4, l15 = lane & 15;
    int row0 = blockIdx.x * 128 + wave * 32;

    const u16* ga0 = A + (size_t)(row0 + l15) * 256 + quad * 8;
    const u16* ga1 = ga0 + 16 * 256;
    const u16* gb = BT + (size_t)l15 * 256 + quad * 8;

    f32x4 acc0[16], acc1[16];
#pragma unroll
    for (int t = 0; t < 16; ++t) { acc0[t] = {0.f, 0.f, 0.f, 0.f}; acc1[t] = {0.f, 0.f, 0.f, 0.f}; }

#pragma unroll 2
    for (int kb = 0; kb < 8; ++kb) {
        bf16x8 af0 = *(const bf16x8*)(ga0 + kb * 32);
        bf16x8 af1 = *(const bf16x8*)(ga1 + kb * 32);
#pragma unroll
        for (int t = 0; t < 16; ++t) {
            bf16x8 bf = *(const bf16x8*)(gb + (size_t)t * 4096 + kb * 32);
            acc0[t] = __builtin_amdgcn_mfma_f32_16x16x32_bf16(af0, bf, acc0[t], 0, 0, 0);
            acc1[t] = __builtin_amdgcn_mfma_f32_16x16x32_bf16(af1, bf, acc1[t], 0, 0, 0);
        }
    }

#pragma unroll
    for (int rf = 0; rf < 2; ++rf) {
        f32x4* acc = rf ? acc1 : acc0;
        int rbase = row0 + rf * 16 + quad * 4;
        if (MODE == 0) {
#pragma unroll
            for (int t = 0; t < 16; ++t) {
                float bv = bias[t * 16 + l15];
#pragma unroll
                for (int i = 0; i < 4; ++i) acc[t][i] += bv;
            }
#pragma unroll
            for (int i = 0; i < 4; ++i) {
                float s = 0.f, q = 0.f;
#pragma unroll
                for (int t = 0; t < 16; ++t) { float v = acc[t][i]; s += v; q += v * v; }
                for (int off = 1; off < 16; off <<= 1) {
                    s += __shfl_xor(s, off);
                    q += __shfl_xor(q, off);
                }
                float mu = s * (1.0f / 256.0f);
                float var = q * (1.0f / 256.0f) - mu * mu;
                float rs = rsqrtf(var + LN_EPS);
                int row = rbase + i;
#pragma unroll
                for (int t = 0; t < 16; ++t) {
                    int c = t * 16 + l15;
                    float v = (acc[t][i] - mu) * rs * g[c] + be[c];
                    float ge = 0.5f * v * (1.0f + erff(v * 0.70710678118f));
                    xb_out[(size_t)row * 256 + c] = f2bf(ge);
                }
            }
        } else {
#pragma unroll
            for (int i = 0; i < 4; ++i) {
                int row = rbase + i;
                if (row < N_NODES) {
#pragma unroll
                    for (int t = 0; t < 16; ++t) {
                        int c = t * 16 + l15;
                        f_out[(size_t)row * 256 + c] = acc[t][i] + bias[c];
                    }
                }
            }
        }
    }
}

extern "C" void kernel_launch(void* const* d_in, const int* in_sizes, int n_in,
                              void* d_out, int out_size, void* d_ws, size_t ws_size,
                              hipStream_t stream) {
    const float* nodef = (const float*)d_in[0];
    const int*   src   = (const int*)d_in[1];
    const int*   dst   = (const int*)d_in[2];
    const float* ew    = (const float*)d_in[3];
    const float* W1 = (const float*)d_in[4];
    const float* b1 = (const float*)d_in[5];
    const float* g1 = (const float*)d_in[6];
    const float* be1 = (const float*)d_in[7];
    const float* W2 = (const float*)d_in[8];
    const float* b2 = (const float*)d_in[9];
    const float* g2 = (const float*)d_in[10];
    const float* be2 = (const float*)d_in[11];
    const float* Wp = (const float*)d_in[12];
    const float* bp = (const float*)d_in[13];
    float* out = (float*)d_out;

    char* ws = (char*)d_ws;
    size_t off = 0;
    auto alloc = [&](size_t bytes) -> void* {
        void* p = ws + off;
        off += (bytes + 255) & ~(size_t)255;
        return p;
    };
    u16*   ybuf    = (u16*)alloc((size_t)MPAD * 256 * 2);
    u16*   xbuf    = (u16*)alloc((size_t)MPAD * 256 * 2);
    u16*   WT      = (u16*)alloc((size_t)3 * 65536 * 2);
    int*   counts  = (int*)alloc((size_t)N_NODES * 4);
    int*   offsets = (int*)alloc((size_t)(N_NODES + 1) * 4);
    int*   cursor  = (int*)alloc((size_t)N_NODES * 4);
    int*   sperm   = (int*)alloc((size_t)N_EDGES * 4);
    float* wperm   = (float*)alloc((size_t)N_EDGES * 4);
    int*   bsum    = (int*)alloc((size_t)SCAN_BLOCKS * 4);
    int*   bbase   = (int*)alloc((size_t)SCAN_BLOCKS * 4);

    hipMemsetAsync(counts, 0, (size_t)N_NODES * 4, stream);
    count_kernel<<<(N_EDGES + 255) / 256, 256, 0, stream>>>(dst, counts);
    scan1_kernel<<<SCAN_BLOCKS, 256, 0, stream>>>(counts, offsets, bsum);
    scan2_kernel<<<1, 256, 0, stream>>>(bsum, bbase);
    scan3_kernel<<<SCAN_BLOCKS, 256, 0, stream>>>(offsets, bbase, cursor);
    scatter_kernel<<<(N_EDGES + 255) / 256, 256, 0, stream>>>(src, dst, ew, cursor, sperm, wperm);
    conv_kernel<<<(N_NODES * 256 / 4) / 256, 256, 0, stream>>>(nodef, xbuf);
    convw_kernel<<<768, 256, 0, stream>>>(W1, W2, Wp, WT);

    const int GB = MPAD / 128;  // 391 gemm blocks
    // layer 1  (xbuf holds bf16 node features; gemm1 overwrites it after spmm consumed it)
    spmm_kernel<<<(N_NODES + 3) / 4, 256, 0, stream>>>(xbuf, offsets, sperm, wperm, ybuf);
    gemm_kernel<0><<<GB, 256, 0, stream>>>(ybuf, WT, b1, g1, be1, xbuf, nullptr);
    // layer 2
    spmm_kernel<<<(N_NODES + 3) / 4, 256, 0, stream>>>(xbuf, offsets, sperm, wperm, ybuf);
    gemm_kernel<0><<<GB, 256, 0, stream>>>(ybuf, WT + 65536, b2, g2, be2, xbuf, nullptr);
    // projection
    gemm_kernel<1><<<GB, 256, 0, stream>>>(xbuf, WT + 2 * 65536, bp, nullptr, nullptr, nullptr, out);
}

// Round 5
// 447.705 us; speedup vs baseline: 1.4898x; 1.1388x over previous
//
#include <hip/hip_runtime.h>
#include <hip/hip_bf16.h>
#include <math.h>

#define N_NODES 50000
#define N_EDGES 800000
#define DIM 256
#define MPAD 50176   /* 196 gemm blocks * 256 rows; 3136 tiles of 16 rows */
#define LN_EPS 1e-5f
#define SCAN_BLOCKS 196  /* 196*256 = 50176 >= N_NODES */
#define LDB 264          /* padded LDS B stride in u16: row advance=4 banks -> 2 lanes/bank (free) */

typedef short bf16x8 __attribute__((ext_vector_type(8)));
typedef float f32x4 __attribute__((ext_vector_type(4)));
typedef unsigned short u16;
typedef u16 u16x8 __attribute__((ext_vector_type(8)));

__device__ __forceinline__ u16 f2bf(float f) {
    union { float f; unsigned u; } v; v.f = f;
    unsigned r = (v.u + 0x7FFFu + ((v.u >> 16) & 1u)) >> 16;
    return (u16)r;
}
__device__ __forceinline__ float bf2f(u16 h) {
    union { unsigned u; float f; } v; v.u = ((unsigned)h) << 16;
    return v.f;
}
// tanh-form gelu via sigmoid: max |err| vs exact ~3e-3, well inside tolerance.
__device__ __forceinline__ float gelu_f(float x) {
    float z = x * (1.595769122f + 0.0713548162726f * x * x);
    return x * (1.0f / (1.0f + __expf(-z)));
}

// ---------------- CSR build ----------------
__global__ void count_kernel(const int* __restrict__ dst, int* __restrict__ counts) {
    int e = blockIdx.x * 256 + threadIdx.x;
    if (e < N_EDGES) atomicAdd(&counts[dst[e]], 1);
}

__global__ void scan1_kernel(const int* __restrict__ counts, int* __restrict__ offsets,
                             int* __restrict__ bsum) {
    __shared__ int sh[256];
    int t = threadIdx.x;
    int idx = blockIdx.x * 256 + t;
    int v = (idx < N_NODES) ? counts[idx] : 0;
    sh[t] = v;
    __syncthreads();
#pragma unroll
    for (int off = 1; off < 256; off <<= 1) {
        int u = (t >= off) ? sh[t - off] : 0;
        __syncthreads();
        sh[t] += u;
        __syncthreads();
    }
    if (idx < N_NODES) offsets[idx] = sh[t] - v;
    if (t == 255) bsum[blockIdx.x] = sh[255];
}

__global__ void scan2_kernel(const int* __restrict__ bsum, int* __restrict__ bbase) {
    __shared__ int sh[256];
    int t = threadIdx.x;
    int v = (t < SCAN_BLOCKS) ? bsum[t] : 0;
    sh[t] = v;
    __syncthreads();
#pragma unroll
    for (int off = 1; off < 256; off <<= 1) {
        int u = (t >= off) ? sh[t - off] : 0;
        __syncthreads();
        sh[t] += u;
        __syncthreads();
    }
    if (t < SCAN_BLOCKS) bbase[t] = sh[t] - v;
}

__global__ void scan3_kernel(int* __restrict__ offsets, const int* __restrict__ bbase,
                             int* __restrict__ cursor) {
    int idx = blockIdx.x * 256 + threadIdx.x;
    if (idx < N_NODES) {
        int o = offsets[idx] + bbase[blockIdx.x];
        offsets[idx] = o;
        cursor[idx] = o;
    }
    if (idx == 0) offsets[N_NODES] = N_EDGES;
}

__global__ void scatter_kernel(const int* __restrict__ src, const int* __restrict__ dst,
                               const float* __restrict__ w, int* __restrict__ cursor,
                               int* __restrict__ sperm, float* __restrict__ wperm) {
    int e = blockIdx.x * 256 + threadIdx.x;
    if (e < N_EDGES) {
        int d = dst[e];
        int p = atomicAdd(&cursor[d], 1);
        sperm[p] = src[e];
        wperm[p] = w[e];
    }
}

// ---------------- f32 -> bf16 row conversion (row-major out) ----------------
__global__ void conv_kernel(const float* __restrict__ in, u16* __restrict__ out) {
    int i = blockIdx.x * 256 + threadIdx.x;
    float4 v = ((const float4*)in)[i];
    ushort4 o;
    o.x = f2bf(v.x); o.y = f2bf(v.y); o.z = f2bf(v.z); o.w = f2bf(v.w);
    ((ushort4*)out)[i] = o;
}

// ---------------- weight transpose + bf16 convert ----------------
// WT[m][n][k] = bf16(W_m[k][n]);  m in {0:W1, 1:W2, 2:Wp}
__global__ void convw_kernel(const float* __restrict__ W1, const float* __restrict__ W2,
                             const float* __restrict__ Wp, u16* __restrict__ WT) {
    int idx = blockIdx.x * 256 + threadIdx.x;
    int m = idx >> 16;
    int r = idx & 65535;
    int n = r >> 8, k = r & 255;
    const float* W = (m == 0) ? W1 : (m == 1) ? W2 : Wp;
    WT[idx] = f2bf(W[k * 256 + n]);
}

// ---------------- SPMM: y = x + adj-weighted gather-sum; TILED bf16 output ----
// Block = one 16-row tile (16 nodes), 4 waves x 4 nodes. Gather input x is
// ROW-major bf16. Output written via LDS tile staging as 8 coalesced 1KB
// stores in MFMA-A-fragment order: granule g = kb*64 + quad*16 + l15 at g*16B
// holds row l15, k = kb*32+quad*8..+8. Single-CU tile writes (no cross-XCD
// partial-line merging).
__global__ __launch_bounds__(256) void spmm_kernel(
        const u16* __restrict__ x, const int* __restrict__ offs,
        const int* __restrict__ sperm, const float* __restrict__ wperm,
        u16* __restrict__ y) {
    __shared__ u16 tile[16 * 256];  // 8 KB, row-major staging
    int tid = threadIdx.x;
    int wave = tid >> 6;
    int lane = tid & 63;
    int node0 = blockIdx.x * 16 + wave * 4;  // grid covers exactly N_NODES/16 tiles

    const ushort4* xv = (const ushort4*)x;
#pragma unroll 1
    for (int i = 0; i < 4; ++i) {
        int node = node0 + i;
        ushort4 v = xv[(size_t)node * 64 + lane];
        float a0 = bf2f(v.x), a1 = bf2f(v.y), a2 = bf2f(v.z), a3 = bf2f(v.w);
        float b0 = 0, b1 = 0, b2 = 0, b3 = 0;
        float c0 = 0, c1 = 0, c2 = 0, c3 = 0;
        float d0 = 0, d1 = 0, d2 = 0, d3 = 0;

        int p = offs[node];
        int p1 = offs[node + 1];
        for (; p + 4 <= p1; p += 4) {
            int s0 = sperm[p], s1 = sperm[p + 1], s2 = sperm[p + 2], s3 = sperm[p + 3];
            float w0 = wperm[p], w1 = wperm[p + 1], w2 = wperm[p + 2], w3 = wperm[p + 3];
            ushort4 v0 = xv[(size_t)s0 * 64 + lane];
            ushort4 v1 = xv[(size_t)s1 * 64 + lane];
            ushort4 v2 = xv[(size_t)s2 * 64 + lane];
            ushort4 v3 = xv[(size_t)s3 * 64 + lane];
            a0 += w0 * bf2f(v0.x); a1 += w0 * bf2f(v0.y); a2 += w0 * bf2f(v0.z); a3 += w0 * bf2f(v0.w);
            b0 += w1 * bf2f(v1.x); b1 += w1 * bf2f(v1.y); b2 += w1 * bf2f(v1.z); b3 += w1 * bf2f(v1.w);
            c0 += w2 * bf2f(v2.x); c1 += w2 * bf2f(v2.y); c2 += w2 * bf2f(v2.z); c3 += w2 * bf2f(v2.w);
            d0 += w3 * bf2f(v3.x); d1 += w3 * bf2f(v3.y); d2 += w3 * bf2f(v3.z); d3 += w3 * bf2f(v3.w);
        }
        for (; p < p1; ++p) {
            int s = sperm[p];
            float w = wperm[p];
            ushort4 vv = xv[(size_t)s * 64 + lane];
            a0 += w * bf2f(vv.x); a1 += w * bf2f(vv.y); a2 += w * bf2f(vv.z); a3 += w * bf2f(vv.w);
        }
        a0 += b0 + c0 + d0; a1 += b1 + c1 + d1;
        a2 += b2 + c2 + d2; a3 += b3 + c3 + d3;
        ushort4 o;
        o.x = f2bf(a0); o.y = f2bf(a1); o.z = f2bf(a2); o.w = f2bf(a3);
        ((ushort4*)&tile[(wave * 4 + i) * 256])[lane] = o;
    }
    __syncthreads();
    // write tile in fragment order: 512 granules of 16B, 2 per thread
    u16* outb = y + (size_t)blockIdx.x * 4096;
#pragma unroll
    for (int h = 0; h < 2; ++h) {
        int gI = tid + h * 256;
        int r = gI & 15;
        int k0 = (gI >> 6) * 32 + ((gI >> 4) & 3) * 8;
        u16x8 v = *(const u16x8*)&tile[r * 256 + k0];
        *(u16x8*)(outb + (size_t)gI * 8) = v;
    }
}

// ---------------- GEMM: tiled-A, B fully LDS-resident, barrier-free K-loop ----
// 256 rows/block (4 waves x 4 row-frags), grid 196. A is TILED: each A-frag is
// one contiguous 1KB wave-load at base + lane*16 (prefetched 1 kb ahead).
// B (256x256 bf16) staged once into padded LDS; 16 ds_read_b128 + 64 MFMA per kb.
// MODE 0: activation out = bf16(gelu(LN(A@B+bias))); OUT_TILED picks row-major
//         (feeds spmm gather) or tiled (feeds next GEMM, in-place over A is safe
//         since each block reads/writes only its own tiles).
// MODE 1: f_out = A@B + bias (f32 row-major, guarded).
template <int MODE, int OUT_TILED>
__global__ __launch_bounds__(256, 1) void gemm_kernel(
        const u16* __restrict__ A, const u16* __restrict__ BT,
        const float* __restrict__ bias, const float* __restrict__ g,
        const float* __restrict__ be, u16* __restrict__ xb_out,
        float* __restrict__ f_out) {
    __shared__ u16 b_lds[256 * LDB];  // 135168 B
    int tid = threadIdx.x;
    int wave = tid >> 6, lane = tid & 63;
    int quad = lane >> 4, l15 = lane & 15;

    // ---- stage B (coalesced 1KB global loads -> padded LDS) ----
#pragma unroll
    for (int i = 0; i < 32; ++i) {
        int c = i * 256 + tid;  // chunk of 8 u16
        u16x8 v = *(const u16x8*)(BT + (size_t)c * 8);
        *(u16x8*)&b_lds[(c >> 5) * LDB + (c & 31) * 8] = v;
    }

    // ---- A-frag pointers (tiled layout), prefetch kb=0 ----
    int tbase = blockIdx.x * 16 + wave * 4;
    const u16* ga0 = A + (size_t)(tbase + 0) * 4096 + lane * 8;
    const u16* ga1 = A + (size_t)(tbase + 1) * 4096 + lane * 8;
    const u16* ga2 = A + (size_t)(tbase + 2) * 4096 + lane * 8;
    const u16* ga3 = A + (size_t)(tbase + 3) * 4096 + lane * 8;
    bf16x8 p0 = *(const bf16x8*)ga0;
    bf16x8 p1 = *(const bf16x8*)ga1;
    bf16x8 p2 = *(const bf16x8*)ga2;
    bf16x8 p3 = *(const bf16x8*)ga3;

    f32x4 acc[4][16];
#pragma unroll
    for (int rf = 0; rf < 4; ++rf)
#pragma unroll
        for (int t = 0; t < 16; ++t) acc[rf][t] = {0.f, 0.f, 0.f, 0.f};

    __syncthreads();  // B resident (also drains kb0 prefetch - needed anyway)

#pragma unroll
    for (int kb = 0; kb < 8; ++kb) {
        bf16x8 a0 = p0, a1 = p1, a2 = p2, a3 = p3;
        if (kb < 7) {
            p0 = *(const bf16x8*)(ga0 + (kb + 1) * 512);
            p1 = *(const bf16x8*)(ga1 + (kb + 1) * 512);
            p2 = *(const bf16x8*)(ga2 + (kb + 1) * 512);
            p3 = *(const bf16x8*)(ga3 + (kb + 1) * 512);
        }
        const u16* bl = &b_lds[l15 * LDB + kb * 32 + quad * 8];
#pragma unroll
        for (int t = 0; t < 16; ++t) {
            bf16x8 bf = *(const bf16x8*)(bl + t * 16 * LDB);
            acc[0][t] = __builtin_amdgcn_mfma_f32_16x16x32_bf16(a0, bf, acc[0][t], 0, 0, 0);
            acc[1][t] = __builtin_amdgcn_mfma_f32_16x16x32_bf16(a1, bf, acc[1][t], 0, 0, 0);
            acc[2][t] = __builtin_amdgcn_mfma_f32_16x16x32_bf16(a2, bf, acc[2][t], 0, 0, 0);
            acc[3][t] = __builtin_amdgcn_mfma_f32_16x16x32_bf16(a3, bf, acc[3][t], 0, 0, 0);
        }
    }

    int rowblk = blockIdx.x * 256 + wave * 64;
#pragma unroll
    for (int rf = 0; rf < 4; ++rf) {
        int rbase = rowblk + rf * 16 + quad * 4;
        if (MODE == 0) {
#pragma unroll
            for (int t = 0; t < 16; ++t) {
                float bv = bias[t * 16 + l15];
#pragma unroll
                for (int i = 0; i < 4; ++i) acc[rf][t][i] += bv;
            }
#pragma unroll
            for (int i = 0; i < 4; ++i) {
                float s = 0.f, q = 0.f;
#pragma unroll
                for (int t = 0; t < 16; ++t) { float v = acc[rf][t][i]; s += v; q += v * v; }
                for (int off = 1; off < 16; off <<= 1) {
                    s += __shfl_xor(s, off);
                    q += __shfl_xor(q, off);
                }
                float mu = s * (1.0f / 256.0f);
                float var = q * (1.0f / 256.0f) - mu * mu;
                float rs = rsqrtf(var + LN_EPS);
                int row = rbase + i;
#pragma unroll
                for (int t = 0; t < 16; ++t) {
                    int c = t * 16 + l15;
                    float v = (acc[rf][t][i] - mu) * rs * g[c] + be[c];
                    u16 ob = f2bf(gelu_f(v));
                    if (OUT_TILED) {
                        size_t o = (size_t)(row >> 4) * 4096 + (c >> 5) * 512 +
                                   ((c >> 3) & 3) * 128 + (row & 15) * 8 + (c & 7);
                        xb_out[o] = ob;
                    } else {
                        xb_out[(size_t)row * 256 + c] = ob;
                    }
                }
            }
        } else {
#pragma unroll
            for (int i = 0; i < 4; ++i) {
                int row = rbase + i;
                if (row < N_NODES) {
#pragma unroll
                    for (int t = 0; t < 16; ++t) {
                        int c = t * 16 + l15;
                        f_out[(size_t)row * 256 + c] = acc[rf][t][i] + bias[c];
                    }
                }
            }
        }
    }
}

extern "C" void kernel_launch(void* const* d_in, const int* in_sizes, int n_in,
                              void* d_out, int out_size, void* d_ws, size_t ws_size,
                              hipStream_t stream) {
    const float* nodef = (const float*)d_in[0];
    const int*   src   = (const int*)d_in[1];
    const int*   dst   = (const int*)d_in[2];
    const float* ew    = (const float*)d_in[3];
    const float* W1 = (const float*)d_in[4];
    const float* b1 = (const float*)d_in[5];
    const float* g1 = (const float*)d_in[6];
    const float* be1 = (const float*)d_in[7];
    const float* W2 = (const float*)d_in[8];
    const float* b2 = (const float*)d_in[9];
    const float* g2 = (const float*)d_in[10];
    const float* be2 = (const float*)d_in[11];
    const float* Wp = (const float*)d_in[12];
    const float* bp = (const float*)d_in[13];
    float* out = (float*)d_out;

    char* ws = (char*)d_ws;
    size_t off = 0;
    auto alloc = [&](size_t bytes) -> void* {
        void* p = ws + off;
        off += (bytes + 255) & ~(size_t)255;
        return p;
    };
    u16*   ybuf    = (u16*)alloc((size_t)MPAD * 256 * 2);  // tiled activations
    u16*   xbuf    = (u16*)alloc((size_t)MPAD * 256 * 2);  // row-major activations
    u16*   WT      = (u16*)alloc((size_t)3 * 65536 * 2);
    int*   counts  = (int*)alloc((size_t)N_NODES * 4);
    int*   offsets = (int*)alloc((size_t)(N_NODES + 1) * 4);
    int*   cursor  = (int*)alloc((size_t)N_NODES * 4);
    int*   sperm   = (int*)alloc((size_t)N_EDGES * 4);
    float* wperm   = (float*)alloc((size_t)N_EDGES * 4);
    int*   bsum    = (int*)alloc((size_t)SCAN_BLOCKS * 4);
    int*   bbase   = (int*)alloc((size_t)SCAN_BLOCKS * 4);

    hipMemsetAsync(counts, 0, (size_t)N_NODES * 4, stream);
    count_kernel<<<(N_EDGES + 255) / 256, 256, 0, stream>>>(dst, counts);
    scan1_kernel<<<SCAN_BLOCKS, 256, 0, stream>>>(counts, offsets, bsum);
    scan2_kernel<<<1, 256, 0, stream>>>(bsum, bbase);
    scan3_kernel<<<SCAN_BLOCKS, 256, 0, stream>>>(offsets, bbase, cursor);
    scatter_kernel<<<(N_EDGES + 255) / 256, 256, 0, stream>>>(src, dst, ew, cursor, sperm, wperm);
    conv_kernel<<<N_NODES * 64 / 256, 256, 0, stream>>>(nodef, xbuf);
    convw_kernel<<<768, 256, 0, stream>>>(W1, W2, Wp, WT);

    const int GB = MPAD / 256;        // 196 gemm blocks
    const int SB = N_NODES / 16;      // 3125 spmm tile-blocks (exact)
    // layer 1: gather x(row-major) -> ybuf(tiled); gemm -> xbuf(row-major)
    spmm_kernel<<<SB, 256, 0, stream>>>(xbuf, offsets, sperm, wperm, ybuf);
    gemm_kernel<0, 0><<<GB, 256, 0, stream>>>(ybuf, WT, b1, g1, be1, xbuf, nullptr);
    // layer 2: gather xbuf -> ybuf(tiled); gemm -> ybuf IN-PLACE (tiled)
    spmm_kernel<<<SB, 256, 0, stream>>>(xbuf, offsets, sperm, wperm, ybuf);
    gemm_kernel<0, 1><<<GB, 256, 0, stream>>>(ybuf, WT + 65536, b2, g2, be2, ybuf, nullptr);
    // projection: tiled A -> f32 row-major out
    gemm_kernel<1, 0><<<GB, 256, 0, stream>>>(ybuf, WT + 2 * 65536, bp, nullptr, nullptr, nullptr, out);
}

// Round 6
// 447.475 us; speedup vs baseline: 1.4906x; 1.0005x over previous
//
#include <hip/hip_runtime.h>
#include <hip/hip_bf16.h>
#include <math.h>

#define N_NODES 50000
#define N_EDGES 800000
#define DIM 256
#define MPAD 50176   /* 196 gemm blocks * 256 rows; 1568 tiles of 32 rows */
#define LN_EPS 1e-5f
#define SCAN_BLOCKS 196  /* 196*256 = 50176 >= N_NODES */

typedef short bf16x8 __attribute__((ext_vector_type(8)));
typedef float f32x16 __attribute__((ext_vector_type(16)));
typedef unsigned short u16;
typedef u16 u16x8 __attribute__((ext_vector_type(8)));

__device__ __forceinline__ u16 f2bf(float f) {
    union { float f; unsigned u; } v; v.f = f;
    unsigned r = (v.u + 0x7FFFu + ((v.u >> 16) & 1u)) >> 16;
    return (u16)r;
}
__device__ __forceinline__ float bf2f(u16 h) {
    union { unsigned u; float f; } v; v.u = ((unsigned)h) << 16;
    return v.f;
}
// tanh-form gelu via sigmoid: max |err| vs exact ~3e-3, inside tolerance.
__device__ __forceinline__ float gelu_f(float x) {
    float z = x * (1.595769122f + 0.0713548162726f * x * x);
    return x * (1.0f / (1.0f + __expf(-z)));
}

// ---------------- CSR build ----------------
__global__ void count_kernel(const int* __restrict__ dst, int* __restrict__ counts) {
    int e = blockIdx.x * 256 + threadIdx.x;
    if (e < N_EDGES) atomicAdd(&counts[dst[e]], 1);
}

__global__ void scan1_kernel(const int* __restrict__ counts, int* __restrict__ offsets,
                             int* __restrict__ bsum) {
    __shared__ int sh[256];
    int t = threadIdx.x;
    int idx = blockIdx.x * 256 + t;
    int v = (idx < N_NODES) ? counts[idx] : 0;
    sh[t] = v;
    __syncthreads();
#pragma unroll
    for (int off = 1; off < 256; off <<= 1) {
        int u = (t >= off) ? sh[t - off] : 0;
        __syncthreads();
        sh[t] += u;
        __syncthreads();
    }
    if (idx < N_NODES) offsets[idx] = sh[t] - v;
    if (t == 255) bsum[blockIdx.x] = sh[255];
}

__global__ void scan2_kernel(const int* __restrict__ bsum, int* __restrict__ bbase) {
    __shared__ int sh[256];
    int t = threadIdx.x;
    int v = (t < SCAN_BLOCKS) ? bsum[t] : 0;
    sh[t] = v;
    __syncthreads();
#pragma unroll
    for (int off = 1; off < 256; off <<= 1) {
        int u = (t >= off) ? sh[t - off] : 0;
        __syncthreads();
        sh[t] += u;
        __syncthreads();
    }
    if (t < SCAN_BLOCKS) bbase[t] = sh[t] - v;
}

__global__ void scan3_kernel(int* __restrict__ offsets, const int* __restrict__ bbase,
                             int* __restrict__ cursor) {
    int idx = blockIdx.x * 256 + threadIdx.x;
    if (idx < N_NODES) {
        int o = offsets[idx] + bbase[blockIdx.x];
        offsets[idx] = o;
        cursor[idx] = o;
    }
    if (idx == 0) offsets[N_NODES] = N_EDGES;
}

__global__ void scatter_kernel(const int* __restrict__ src, const int* __restrict__ dst,
                               const float* __restrict__ w, int* __restrict__ cursor,
                               int* __restrict__ sperm, float* __restrict__ wperm) {
    int e = blockIdx.x * 256 + threadIdx.x;
    if (e < N_EDGES) {
        int d = dst[e];
        int p = atomicAdd(&cursor[d], 1);
        sperm[p] = src[e];
        wperm[p] = w[e];
    }
}

// ---------------- f32 -> bf16 row conversion (row-major out) ----------------
__global__ void conv_kernel(const float* __restrict__ in, u16* __restrict__ out) {
    int i = blockIdx.x * 256 + threadIdx.x;
    float4 v = ((const float4*)in)[i];
    ushort4 o;
    o.x = f2bf(v.x); o.y = f2bf(v.y); o.z = f2bf(v.z); o.w = f2bf(v.w);
    ((ushort4*)out)[i] = o;
}

// ---------------- weight transpose + bf16 convert ----------------
// WT[m][n][k] = bf16(W_m[k][n]);  m in {0:W1, 1:W2, 2:Wp}
__global__ void convw_kernel(const float* __restrict__ W1, const float* __restrict__ W2,
                             const float* __restrict__ Wp, u16* __restrict__ WT) {
    int idx = blockIdx.x * 256 + threadIdx.x;
    int m = idx >> 16;
    int r = idx & 65535;
    int n = r >> 8, k = r & 255;
    const float* W = (m == 0) ? W1 : (m == 1) ? W2 : Wp;
    WT[idx] = f2bf(W[k * 256 + n]);
}

// ---------------- SPMM: y = x + gather-sum; TILED-32 bf16 output ----------------
// Block = one 32-row tile, 4 waves x 8 nodes. Gather input x is ROW-major bf16.
// Output layout (matches mfma_32x32x16 A-fragment): tile T, granule
// gi = kb*64 + half*32 + m  (kb in 0..15, half = k-half, m = row in tile)
// at T*8192 + gi*8 holds row m, k = kb*16 + half*8 .. +8.
__global__ __launch_bounds__(256) void spmm_kernel(
        const u16* __restrict__ x, const int* __restrict__ offs,
        const int* __restrict__ sperm, const float* __restrict__ wperm,
        u16* __restrict__ y) {
    __shared__ u16 tile[32 * 264];  // padded rows: 16.9 KB
    int tid = threadIdx.x;
    int wave = tid >> 6;
    int lane = tid & 63;
    int node0 = blockIdx.x * 32 + wave * 8;

    const ushort4* xv = (const ushort4*)x;
#pragma unroll 1
    for (int i = 0; i < 8; ++i) {
        int node = node0 + i;
        float a0 = 0, a1 = 0, a2 = 0, a3 = 0;
        float b0 = 0, b1 = 0, b2 = 0, b3 = 0;
        float c0 = 0, c1 = 0, c2 = 0, c3 = 0;
        float d0 = 0, d1 = 0, d2 = 0, d3 = 0;
        if (node < N_NODES) {
            ushort4 v = xv[(size_t)node * 64 + lane];
            a0 = bf2f(v.x); a1 = bf2f(v.y); a2 = bf2f(v.z); a3 = bf2f(v.w);
            int p = offs[node];
            int p1 = offs[node + 1];
            for (; p + 4 <= p1; p += 4) {
                int s0 = sperm[p], s1 = sperm[p + 1], s2 = sperm[p + 2], s3 = sperm[p + 3];
                float w0 = wperm[p], w1 = wperm[p + 1], w2 = wperm[p + 2], w3 = wperm[p + 3];
                ushort4 v0 = xv[(size_t)s0 * 64 + lane];
                ushort4 v1 = xv[(size_t)s1 * 64 + lane];
                ushort4 v2 = xv[(size_t)s2 * 64 + lane];
                ushort4 v3 = xv[(size_t)s3 * 64 + lane];
                a0 += w0 * bf2f(v0.x); a1 += w0 * bf2f(v0.y); a2 += w0 * bf2f(v0.z); a3 += w0 * bf2f(v0.w);
                b0 += w1 * bf2f(v1.x); b1 += w1 * bf2f(v1.y); b2 += w1 * bf2f(v1.z); b3 += w1 * bf2f(v1.w);
                c0 += w2 * bf2f(v2.x); c1 += w2 * bf2f(v2.y); c2 += w2 * bf2f(v2.z); c3 += w2 * bf2f(v2.w);
                d0 += w3 * bf2f(v3.x); d1 += w3 * bf2f(v3.y); d2 += w3 * bf2f(v3.z); d3 += w3 * bf2f(v3.w);
            }
            for (; p < p1; ++p) {
                int s = sperm[p];
                float w = wperm[p];
                ushort4 vv = xv[(size_t)s * 64 + lane];
                a0 += w * bf2f(vv.x); a1 += w * bf2f(vv.y); a2 += w * bf2f(vv.z); a3 += w * bf2f(vv.w);
            }
            a0 += b0 + c0 + d0; a1 += b1 + c1 + d1;
            a2 += b2 + c2 + d2; a3 += b3 + c3 + d3;
        }
        ushort4 o;
        o.x = f2bf(a0); o.y = f2bf(a1); o.z = f2bf(a2); o.w = f2bf(a3);
        ((ushort4*)&tile[(wave * 8 + i) * 264])[lane] = o;
    }
    __syncthreads();
    // write tile in 32x32x16 A-fragment granule order: 1024 granules, 4/thread
    u16* outb = y + (size_t)blockIdx.x * 8192;
#pragma unroll
    for (int hh = 0; hh < 4; ++hh) {
        int gi = tid + hh * 256;
        int kb = gi >> 6;
        int rem = gi & 63;
        int hf = rem >> 5, m = rem & 31;
        u16x8 v = *(const u16x8*)&tile[m * 264 + kb * 16 + hf * 8];
        *(u16x8*)(outb + (size_t)gi * 8) = v;
    }
}

// ---------------- GEMM v3: 32x32x16 MFMA, fragment-tiled LDS B ----------------
// 256 rows/block (4 waves x 2 row-tiles of 32), grid 196, 1 block/CU.
// A tiled-32: A-frag = one contiguous 16B/lane load at tile*8192 + kb*512 + lane*8.
// B staged to LDS in fragment granules, group (t,kb) = 64 granules (1024B) + 16B
// pad (stride 520 u16) -> both staging writes and ds_read_b128 are 8-words/bank
// balanced. Per kb: 2 A-loads (prefetched) + 8 ds_read_b128 + 16 MFMA.
// MODE 0: out = bf16(gelu(LN(A@B+bias))), OUT_TILED: 0=row-major, 1=tiled-32.
// MODE 1: f_out = A@B + bias (f32 row-major, guarded).
template <int MODE, int OUT_TILED>
__global__ __launch_bounds__(256, 1) void gemm_kernel(
        const u16* __restrict__ A, const u16* __restrict__ BT,
        const float* __restrict__ bias, const float* __restrict__ g,
        const float* __restrict__ be, u16* __restrict__ xb_out,
        float* __restrict__ f_out) {
    __shared__ u16 b_lds[128 * 520];  // 133120 B
    int tid = threadIdx.x;
    int wave = tid >> 6, lane = tid & 63;
    int l31 = lane & 31, half = lane >> 5;

    // ---- stage B: 8192 16B-chunks, coalesced reads, granule-scatter writes ----
#pragma unroll 8
    for (int i = 0; i < 32; ++i) {
        int s = i * 256 + tid;
        u16x8 v = *(const u16x8*)(BT + (size_t)s * 8);
        int n = s >> 5, kc = s & 31;
        int t = n >> 5, n32 = n & 31, kb = kc >> 1, hf = kc & 1;
        *(u16x8*)&b_lds[(t * 16 + kb) * 520 + hf * 256 + n32 * 8] = v;
    }

    int tile0 = blockIdx.x * 8 + wave * 2;
    const u16* ga0 = A + (size_t)tile0 * 8192 + lane * 8;
    const u16* ga1 = ga0 + 8192;
    bf16x8 p0 = *(const bf16x8*)ga0;
    bf16x8 p1 = *(const bf16x8*)ga1;

    f32x16 acc[2][8];
#pragma unroll
    for (int rf = 0; rf < 2; ++rf)
#pragma unroll
        for (int t = 0; t < 8; ++t)
#pragma unroll
            for (int r = 0; r < 16; ++r) acc[rf][t][r] = 0.f;

    __syncthreads();

#pragma unroll
    for (int kb = 0; kb < 16; ++kb) {
        bf16x8 a0 = p0, a1 = p1;
        if (kb < 15) {
            p0 = *(const bf16x8*)(ga0 + (kb + 1) * 512);
            p1 = *(const bf16x8*)(ga1 + (kb + 1) * 512);
        }
        const u16* bl = &b_lds[kb * 520 + lane * 8];
#pragma unroll
        for (int t = 0; t < 8; ++t) {
            bf16x8 bf = *(const bf16x8*)(bl + t * 16 * 520);
            acc[0][t] = __builtin_amdgcn_mfma_f32_32x32x16_bf16(a0, bf, acc[0][t], 0, 0, 0);
            acc[1][t] = __builtin_amdgcn_mfma_f32_32x32x16_bf16(a1, bf, acc[1][t], 0, 0, 0);
        }
    }

    // ---- epilogue ----
    float bv[8];
#pragma unroll
    for (int t = 0; t < 8; ++t) bv[t] = bias[t * 32 + l31];

#pragma unroll
    for (int rf = 0; rf < 2; ++rf) {
        int tile = tile0 + rf;
        if (MODE == 0) {
            float gv[8], bev[8];
#pragma unroll
            for (int t = 0; t < 8; ++t) {
                int c = t * 32 + l31;
                gv[t] = g[c]; bev[t] = be[c];
            }
#pragma unroll
            for (int r = 0; r < 16; ++r) {
                float s = 0.f, q = 0.f;
#pragma unroll
                for (int t = 0; t < 8; ++t) {
                    float v = acc[rf][t][r] + bv[t];
                    acc[rf][t][r] = v;
                    s += v; q += v * v;
                }
                for (int off = 1; off < 32; off <<= 1) {
                    s += __shfl_xor(s, off);
                    q += __shfl_xor(q, off);
                }
                float mu = s * (1.0f / 256.0f);
                float var = q * (1.0f / 256.0f) - mu * mu;
                float rs = rsqrtf(var + LN_EPS);
                int m = (r & 3) + 8 * (r >> 2) + 4 * half;
                int row = tile * 32 + m;
#pragma unroll
                for (int t = 0; t < 8; ++t) {
                    int c = t * 32 + l31;
                    float v = (acc[rf][t][r] - mu) * rs * gv[t] + bev[t];
                    u16 ob = f2bf(gelu_f(v));
                    if (OUT_TILED) {
                        size_t o = (size_t)tile * 8192 +
                                   ((size_t)(c >> 4) * 64 + ((c >> 3) & 1) * 32 + m) * 8 + (c & 7);
                        xb_out[o] = ob;
                    } else {
                        xb_out[(size_t)row * 256 + c] = ob;
                    }
                }
            }
        } else {
#pragma unroll
            for (int r = 0; r < 16; ++r) {
                int m = (r & 3) + 8 * (r >> 2) + 4 * half;
                int row = tile * 32 + m;
                if (row < N_NODES) {
#pragma unroll
                    for (int t = 0; t < 8; ++t) {
                        int c = t * 32 + l31;
                        f_out[(size_t)row * 256 + c] = acc[rf][t][r] + bv[t];
                    }
                }
            }
        }
    }
}

extern "C" void kernel_launch(void* const* d_in, const int* in_sizes, int n_in,
                              void* d_out, int out_size, void* d_ws, size_t ws_size,
                              hipStream_t stream) {
    const float* nodef = (const float*)d_in[0];
    const int*   src   = (const int*)d_in[1];
    const int*   dst   = (const int*)d_in[2];
    const float* ew    = (const float*)d_in[3];
    const float* W1 = (const float*)d_in[4];
    const float* b1 = (const float*)d_in[5];
    const float* g1 = (const float*)d_in[6];
    const float* be1 = (const float*)d_in[7];
    const float* W2 = (const float*)d_in[8];
    const float* b2 = (const float*)d_in[9];
    const float* g2 = (const float*)d_in[10];
    const float* be2 = (const float*)d_in[11];
    const float* Wp = (const float*)d_in[12];
    const float* bp = (const float*)d_in[13];
    float* out = (float*)d_out;

    char* ws = (char*)d_ws;
    size_t off = 0;
    auto alloc = [&](size_t bytes) -> void* {
        void* p = ws + off;
        off += (bytes + 255) & ~(size_t)255;
        return p;
    };
    u16*   ybuf    = (u16*)alloc((size_t)MPAD * 256 * 2);  // tiled-32 activations
    u16*   xbuf    = (u16*)alloc((size_t)MPAD * 256 * 2);  // row-major activations
    u16*   WT      = (u16*)alloc((size_t)3 * 65536 * 2);
    int*   counts  = (int*)alloc((size_t)N_NODES * 4);
    int*   offsets = (int*)alloc((size_t)(N_NODES + 1) * 4);
    int*   cursor  = (int*)alloc((size_t)N_NODES * 4);
    int*   sperm   = (int*)alloc((size_t)N_EDGES * 4);
    float* wperm   = (float*)alloc((size_t)N_EDGES * 4);
    int*   bsum    = (int*)alloc((size_t)SCAN_BLOCKS * 4);
    int*   bbase   = (int*)alloc((size_t)SCAN_BLOCKS * 4);

    hipMemsetAsync(counts, 0, (size_t)N_NODES * 4, stream);
    count_kernel<<<(N_EDGES + 255) / 256, 256, 0, stream>>>(dst, counts);
    scan1_kernel<<<SCAN_BLOCKS, 256, 0, stream>>>(counts, offsets, bsum);
    scan2_kernel<<<1, 256, 0, stream>>>(bsum, bbase);
    scan3_kernel<<<SCAN_BLOCKS, 256, 0, stream>>>(offsets, bbase, cursor);
    scatter_kernel<<<(N_EDGES + 255) / 256, 256, 0, stream>>>(src, dst, ew, cursor, sperm, wperm);
    conv_kernel<<<N_NODES * 64 / 256, 256, 0, stream>>>(nodef, xbuf);
    convw_kernel<<<768, 256, 0, stream>>>(W1, W2, Wp, WT);

    const int GB = MPAD / 256;   // 196 gemm blocks
    const int SB = MPAD / 32;    // 1568 spmm tile-blocks (covers all gemm tiles)
    // layer 1: gather xbuf(row-major) -> ybuf(tiled-32); gemm -> xbuf(row-major)
    spmm_kernel<<<SB, 256, 0, stream>>>(xbuf, offsets, sperm, wperm, ybuf);
    gemm_kernel<0, 0><<<GB, 256, 0, stream>>>(ybuf, WT, b1, g1, be1, xbuf, nullptr);
    // layer 2: gather xbuf -> ybuf(tiled-32); gemm -> ybuf IN-PLACE (tiled-32)
    spmm_kernel<<<SB, 256, 0, stream>>>(xbuf, offsets, sperm, wperm, ybuf);
    gemm_kernel<0, 1><<<GB, 256, 0, stream>>>(ybuf, WT + 65536, b2, g2, be2, ybuf, nullptr);
    // projection: tiled-32 A -> f32 row-major out
    gemm_kernel<1, 0><<<GB, 256, 0, stream>>>(ybuf, WT + 2 * 65536, bp, nullptr, nullptr, nullptr, out);
}